// Round 2
// baseline (728.844 us; speedup 1.0000x reference)
//
#include <hip/hip_runtime.h>
#include <math.h>

// ============================================================================
// MoE FFN (dense, E=8): y = sum_e softmax(x@Wr)[:,e] * (gelu(x@W1_e+b1_e)@W2_e+b2_e)
// T=2048, D=1024, H=4096, E=8. FP32 in/out; bf16 MFMA compute.
// R5 -> R6: (1) branch-free A&S-7.1.26 erf GELU (~13 VALU vs ~50 for libm
// erff; 67M calls in gemm1 epilogue were ~44% VALUBusy). (2) mainloop drain
// relaxed: no lgkmcnt(0)/sched_barrier before MFMA cluster -- compiler emits
// progressive counted lgkmcnt (m97 evidence); correctness needs lgkmcnt(0)
// only AT the barrier (fused with vmcnt(8)). Reads ordered bv then af, MFMA
// mi-major so first MFMA needs only 5/12 reads. (3) transconv: 4 rows/thread,
// bf16x4 8B stores (was scalar 2B).
// Ring-4 LDS (128 KiB), stage depth 3, vmcnt(8) steady state (T3/T4),
// setprio around MFMA (T5), bijective XCD swizzle (T1), swizzled GLL source
// chunk c ^ ((row>>1)&3) for conflict-free ds_read_b128 (T2, both-sides).
// ws tiers: A >=214MB (batched), B >=37.9MB (per-expert), D zero-ws fallback.
// ============================================================================

typedef float f32x4 __attribute__((ext_vector_type(4)));
typedef __bf16 bf16x8 __attribute__((ext_vector_type(8)));
typedef __bf16 bf16x4 __attribute__((ext_vector_type(4)));

#define GLL16(gp, lp)                                                          \
  __builtin_amdgcn_global_load_lds(                                            \
      (const __attribute__((address_space(1))) void*)(gp),                     \
      (__attribute__((address_space(3))) void*)(lp), 16, 0, 0)

// Branch-free exact-enough GELU: erf via Abramowitz-Stegun 7.1.26
// (|err| <= 1.5e-7, far below bf16 store quantization). ~13 VALU ops.
__device__ __forceinline__ float gelu_f(float h) {
  float x = h * 0.70710678118654752f;
  float ax = fabsf(x);
  float t = __builtin_amdgcn_rcpf(fmaf(0.3275911f, ax, 1.0f));
  float p = fmaf(1.061405429f, t, -1.453152027f);
  p = fmaf(p, t, 1.421413741f);
  p = fmaf(p, t, -0.284496736f);
  p = fmaf(p, t, 0.254829592f);
  float e = __expf(-x * x);
  float erfv = fmaf(-p * t, e, 1.0f);  // 1 - poly(t)*exp(-x^2)
  erfv = copysignf(erfv, x);
  return 0.5f * h * (1.0f + erfv);
}

// ---------------------------------------------------------------------------
// Router: logits = x @ rw + rb (fp32), softmax -> P (ws) + probs_out (d_out)
// ---------------------------------------------------------------------------
__global__ void router_kernel(const float* __restrict__ x,
                              const float* __restrict__ rw,
                              const float* __restrict__ rb,
                              float* __restrict__ P,  // may be null (tier D)
                              float* __restrict__ probs_out)
{
  int gid = blockIdx.x * blockDim.x + threadIdx.x;
  int t = gid >> 6;
  int l = gid & 63;
  const float* xr = x + (size_t)t * 1024;
  float a[8];
#pragma unroll
  for (int e = 0; e < 8; ++e) a[e] = 0.f;
  for (int d = l; d < 1024; d += 64) {
    float xv = xr[d];
    f32x4 w0 = *(const f32x4*)(rw + d * 8);
    f32x4 w1 = *(const f32x4*)(rw + d * 8 + 4);
#pragma unroll
    for (int e = 0; e < 4; ++e) a[e] += xv * w0[e];
#pragma unroll
    for (int e = 0; e < 4; ++e) a[4 + e] += xv * w1[e];
  }
#pragma unroll
  for (int off = 32; off > 0; off >>= 1) {
#pragma unroll
    for (int e = 0; e < 8; ++e) a[e] += __shfl_down(a[e], off);
  }
  if (l == 0) {
#pragma unroll
    for (int e = 0; e < 8; ++e) a[e] += rb[e];
    float m = a[0];
#pragma unroll
    for (int e = 1; e < 8; ++e) m = fmaxf(m, a[e]);
    float s = 0.f;
#pragma unroll
    for (int e = 0; e < 8; ++e) { a[e] = __expf(a[e] - m); s += a[e]; }
    float inv = 1.f / s;
#pragma unroll
    for (int e = 0; e < 8; ++e) {
      float p = a[e] * inv;
      if (P) P[t * 8 + e] = p;
      probs_out[t * 8 + e] = p;
    }
  }
}

// ---------------------------------------------------------------------------
// Convert fp32 -> bf16 row-major (for x)
// ---------------------------------------------------------------------------
__global__ void cvt_kernel(const float* __restrict__ src,
                           __bf16* __restrict__ dst)
{
  size_t i = ((size_t)blockIdx.x * 256 + threadIdx.x) * 8;
  f32x4 v0 = *(const f32x4*)(src + i);
  f32x4 v1 = *(const f32x4*)(src + i + 4);
  bf16x8 o;
#pragma unroll
  for (int j = 0; j < 4; ++j) o[j] = (__bf16)v0[j];
#pragma unroll
  for (int j = 0; j < 4; ++j) o[4 + j] = (__bf16)v1[j];
  *(bf16x8*)(dst + i) = o;
}

// ---------------------------------------------------------------------------
// Fused transpose+convert: src fp32 [z][R][C] -> dst bf16 [c][dstLd]+z*zOff+r
// 4 consecutive rows per thread -> bf16x4 (8B) coalesced stores.
// Grid: (R/1024, C/cChunk, Z), 256 threads.
// ---------------------------------------------------------------------------
__global__ void transconv_kernel(const float* __restrict__ src,
                                 __bf16* __restrict__ dst,
                                 int R, int C, int cChunk,
                                 size_t dstLd, size_t zOff)
{
  size_t bs = (size_t)blockIdx.z * (size_t)R * (size_t)C;
  size_t dzo = (size_t)blockIdx.z * zOff;
  int r0 = (blockIdx.x * 256 + threadIdx.x) * 4;
  int c0 = blockIdx.y * cChunk;
  const float* s = src + bs + (size_t)r0 * C;
  for (int c = c0; c < c0 + cChunk; c += 8) {
    float v[4][8];
#pragma unroll
    for (int rr = 0; rr < 4; ++rr) {
      f32x4 a = *(const f32x4*)(s + (size_t)rr * C + c);
      f32x4 b = *(const f32x4*)(s + (size_t)rr * C + c + 4);
#pragma unroll
      for (int j = 0; j < 4; ++j) { v[rr][j] = a[j]; v[rr][4 + j] = b[j]; }
    }
#pragma unroll
    for (int j = 0; j < 8; ++j) {
      bf16x4 o = {(__bf16)v[0][j], (__bf16)v[1][j], (__bf16)v[2][j],
                  (__bf16)v[3][j]};
      *(bf16x4*)(dst + (size_t)(c + j) * dstLd + dzo + r0) = o;
    }
  }
}

// ---------------------------------------------------------------------------
// 256x256 MFMA mainloop, BK=32, ring-4 LDS, counted-vmcnt pipeline.
// C[256x256] += A[256xK] * B[256xK]^T. 8 waves (wm=w>>2, wn=w&3), per-wave
// 128x64 out = 8x4 frags of 16x16x32, 32 MFMA per K-tile per wave.
// Pipeline: tile t+3 staged into ring[(t-1)&3], whose reads (tile t-1) were
// drained by the lgkmcnt(0)-at-barrier of iter t-1. Steady-state wait is
// vmcnt(8) (12 in flight = t+1..t+3; waiting to 8 completes t+1). Intra-tile
// ds_read->MFMA ordering is left to the compiler (progressive counted
// lgkmcnt); reads issued bv[0..3] then af[0..7], MFMA mi-major so the first
// MFMA needs only 5 of 12 reads.
// ---------------------------------------------------------------------------
__device__ __forceinline__ void mfma_loop256(
    const char* Ab, const char* Bb, size_t ldaB, size_t ldbB, int K,
    char* lds, f32x4 acc[8][4])
{
  const int tid = threadIdx.x;
  const int w = tid >> 6, l = tid & 63;
  const int wm = w >> 2, wn = w & 3;
  const int m16 = l & 15, q = l >> 4;
  // read-side swizzle: chunk' = q ^ ((row>>1)&3)
  const int posB = ((q ^ ((m16 >> 1) & 3)) << 4);       // byte offset in row
  const int aE = (wm * 128 + m16) * 64 + posB;          // byte off in A tile
  const int bE = 16384 + (wn * 64 + m16) * 64 + posB;   // byte off (B at +16K)
  // stage-side: row = w*32 + i*16 + (l>>2); src chunk = (l&3) ^ ((l>>3)&3)
  const int sc16 = (((l & 3) ^ ((l >> 3) & 3)) << 4);
  const size_t sAoff = (size_t)(w * 32 + (l >> 2)) * ldaB + sc16;
  const size_t sBoff = (size_t)(w * 32 + (l >> 2)) * ldbB + sc16;
  const int ldst = w * 32 * 64;   // wave's stripe byte offset within a tile
  const int NT = K >> 5;

#define STAGE256(u)                                                            \
  {                                                                            \
    char* dA = lds + (((u) & 3) * 32768) + ldst;                               \
    const char* gA = Ab + sAoff + ((size_t)(u) << 6);                          \
    GLL16(gA, dA);                                                             \
    GLL16(gA + 16 * ldaB, dA + 1024);                                          \
    char* dB = dA + 16384;                                                     \
    const char* gB = Bb + sBoff + ((size_t)(u) << 6);                          \
    GLL16(gB, dB);                                                             \
    GLL16(gB + 16 * ldbB, dB + 1024);                                          \
  }

#define KFRAGS(T)                                                              \
    const char* ring = lds + (((T) & 3) * 32768);                              \
    bf16x8 bv[4], af[8];                                                       \
    _Pragma("unroll") for (int nj = 0; nj < 4; ++nj)                           \
        bv[nj] = *(const bf16x8*)(ring + bE + nj * 1024);                      \
    _Pragma("unroll") for (int mi = 0; mi < 8; ++mi)                           \
        af[mi] = *(const bf16x8*)(ring + aE + mi * 1024);

#define KMFMA                                                                  \
    __builtin_amdgcn_s_setprio(1);                                             \
    _Pragma("unroll") for (int mi = 0; mi < 8; ++mi)                           \
      _Pragma("unroll") for (int nj = 0; nj < 4; ++nj)                         \
        acc[mi][nj] = __builtin_amdgcn_mfma_f32_16x16x32_bf16(                 \
            af[mi], bv[nj], acc[mi][nj], 0, 0, 0);                             \
    __builtin_amdgcn_s_setprio(0);

#define KSYNC(n)                                                               \
    asm volatile("s_waitcnt vmcnt(" #n ") lgkmcnt(0)" ::: "memory");           \
    __builtin_amdgcn_s_barrier();

  // prologue: stage T0..T2 (12 GLL/wave); wait T0 (drain to 8); barrier
  STAGE256(0);
  STAGE256(1);
  STAGE256(2);
  KSYNC(8);

  int t = 0;
  for (; t < NT - 3; ++t) {
    KFRAGS(t);
    STAGE256(t + 3);
    KMFMA;
    KSYNC(8);     // t+1 landed; 8 still in flight
  }
  {  // t = NT-3: drain everything once (tiles NT-2, NT-1 land)
    KFRAGS(t);
    KMFMA;
    KSYNC(0);
  }
  ++t;
  {  // t = NT-2: all data resident, no more LDS writes -> no barriers
    KFRAGS(t);
    KMFMA;
  }
  ++t;
  {  // t = NT-1
    KFRAGS(t);
    KMFMA;
  }
#undef STAGE256
#undef KFRAGS
#undef KMFMA
#undef KSYNC
}

// bijective XCD-chunked block swizzle (nwg % 8 == 0 for all our grids)
__device__ __forceinline__ int xcd_swz(int id, int nwg) {
  return ((nwg & 7) == 0) ? ((id & 7) * (nwg >> 3) + (id >> 3)) : id;
}

// ---------------------------------------------------------------------------
// GEMM1: Hs[t, zcol+h] = P[t,e] * gelu(Xb @ W1T_e^T + b1_e)   (bf16 store)
// grid (8, N/256, Z), 512 threads
// ---------------------------------------------------------------------------
__global__ __launch_bounds__(512, 2) void gemm1_kernel(
    const __bf16* __restrict__ X, const __bf16* __restrict__ W1T,
    const float* __restrict__ b1, const float* __restrict__ P,
    __bf16* __restrict__ Hs, int hs_ld, int e_off, size_t b_zstride)
{
  __shared__ __align__(16) char lds[131072];
  const int nwg = gridDim.x * gridDim.y * gridDim.z;
  const int id = blockIdx.x + gridDim.x * (blockIdx.y + gridDim.y * blockIdx.z);
  const int wg = xcd_swz(id, nwg);
  const int bm = wg & 7;
  const int bn = (wg >> 3) % gridDim.y;
  const int z = wg / (gridDim.y << 3);
  const int e = z + e_off;

  f32x4 acc[8][4];
  const f32x4 z4 = {0.f, 0.f, 0.f, 0.f};
#pragma unroll
  for (int i = 0; i < 8; ++i)
#pragma unroll
    for (int j = 0; j < 4; ++j) acc[i][j] = z4;

  const char* A = (const char*)(X + (size_t)bm * 256 * 1024);
  const char* B = (const char*)(W1T + (size_t)z * b_zstride +
                                (size_t)bn * 256 * 1024);
  mfma_loop256(A, B, 2048, 2048, 1024, lds, acc);

  const int tid = threadIdx.x, w = tid >> 6, l = tid & 63;
  const int wm = w >> 2, wn = w & 3, q = l >> 4, m16 = l & 15;
  const int row0 = bm * 256 + wm * 128 + q * 4;
  const int colE = bn * 256 + wn * 64 + m16;  // expert-local column base
  const int zcol = (hs_ld == 4096) ? 0 : z * 4096;
  float b1v[4];
#pragma unroll
  for (int nj = 0; nj < 4; ++nj)
    b1v[nj] = b1[(size_t)e * 4096 + colE + nj * 16];
#pragma unroll
  for (int mi = 0; mi < 8; ++mi) {
    float pv[4];
#pragma unroll
    for (int r = 0; r < 4; ++r)
      pv[r] = P[(size_t)(row0 + mi * 16 + r) * 8 + e];
#pragma unroll
    for (int nj = 0; nj < 4; ++nj)
#pragma unroll
      for (int r = 0; r < 4; ++r) {
        float h = acc[mi][nj][r] + b1v[nj];
        float o = gelu_f(h) * pv[r];
        Hs[(size_t)(row0 + mi * 16 + r) * hs_ld + zcol + colE + nj * 16] =
            (__bf16)o;
      }
  }
}

// ---------------------------------------------------------------------------
// GEMM2: accb[t,d] += Hs_chunk @ W2T_chunk^T (split-K via z, fp32 atomics)
// grid (8, N/256, Z), 512 threads; per-block K = Kb at offset z*kz
// ---------------------------------------------------------------------------
__global__ __launch_bounds__(512, 2) void gemm2_kernel(
    const __bf16* __restrict__ Hs, const __bf16* __restrict__ W2T,
    float* __restrict__ accb, int lda, int ldb, int kz, int Kb)
{
  __shared__ __align__(16) char lds[131072];
  const int nwg = gridDim.x * gridDim.y * gridDim.z;
  const int id = blockIdx.x + gridDim.x * (blockIdx.y + gridDim.y * blockIdx.z);
  const int wg = xcd_swz(id, nwg);
  const int bm = wg & 7;
  const int bn = (wg >> 3) % gridDim.y;
  const int z = wg / (gridDim.y << 3);

  f32x4 acc[8][4];
  const f32x4 z4 = {0.f, 0.f, 0.f, 0.f};
#pragma unroll
  for (int i = 0; i < 8; ++i)
#pragma unroll
    for (int j = 0; j < 4; ++j) acc[i][j] = z4;

  const char* A = (const char*)(Hs + (size_t)bm * 256 * lda + (size_t)z * kz);
  const char* B = (const char*)(W2T + (size_t)bn * 256 * ldb + (size_t)z * kz);
  mfma_loop256(A, B, (size_t)lda * 2, (size_t)ldb * 2, Kb, lds, acc);

  const int tid = threadIdx.x, w = tid >> 6, l = tid & 63;
  const int wm = w >> 2, wn = w & 3, q = l >> 4, m16 = l & 15;
  const int row0 = bm * 256 + wm * 128 + q * 4;
  const int col0 = bn * 256 + wn * 64 + m16;
#pragma unroll
  for (int mi = 0; mi < 8; ++mi)
#pragma unroll
    for (int nj = 0; nj < 4; ++nj)
#pragma unroll
      for (int r = 0; r < 4; ++r)
        unsafeAtomicAdd(
            accb + (size_t)(row0 + mi * 16 + r) * 1024 + col0 + nj * 16,
            acc[mi][nj][r]);
}

// ---------------------------------------------------------------------------
// Finalize: y = accb + sum_e P*b2   (fp32)
// ---------------------------------------------------------------------------
__global__ void finalize_kernel(const float* __restrict__ accb,
                                const float* __restrict__ P,
                                const float* __restrict__ b2,
                                float* __restrict__ y)
{
  int idx = blockIdx.x * 256 + threadIdx.x;
  int t = idx >> 8;
  int d0 = (idx & 255) << 2;
  f32x4 a = *(const f32x4*)(accb + (size_t)t * 1024 + d0);
#pragma unroll
  for (int e = 0; e < 8; ++e) {
    float p = P[t * 8 + e];
    f32x4 b = *(const f32x4*)(b2 + (size_t)e * 1024 + d0);
#pragma unroll
    for (int c = 0; c < 4; ++c) a[c] += p * b[c];
  }
  *(f32x4*)(y + (size_t)t * 1024 + d0) = a;
}

// ---------------------------------------------------------------------------
// Tier D: zero-workspace fused VALU fallback (fp32)
// ---------------------------------------------------------------------------
__global__ __launch_bounds__(256) void fused_naive_kernel(
    const float* __restrict__ x, const float* __restrict__ w1,
    const float* __restrict__ b1, const float* __restrict__ w2,
    const float* __restrict__ b2, const float* __restrict__ probs,
    float* __restrict__ y)
{
  __shared__ float xs[8][1024];
  __shared__ float gs[8][64];
  __shared__ float ps[8];
  const int tid = threadIdx.x;
  const int t0 = blockIdx.x * 8;
  const size_t DH = (size_t)1024 * 4096;
  const int tt = tid >> 5;
  const int d0 = (tid & 31) * 32;
  float acc[32];
#pragma unroll
  for (int i = 0; i < 32; ++i) acc[i] = 0.f;
  {
    const f32x4* xsrc = (const f32x4*)(x + (size_t)t0 * 1024);
    f32x4* xdst = (f32x4*)&xs[0][0];
    for (int i = tid; i < 2048; i += 256) xdst[i] = xsrc[i];
  }
  const int wv = tid >> 6;
  const int hl = tid & 63;
  for (int e = 0; e < 8; ++e) {
    if (tid < 8) ps[tid] = probs[(size_t)(t0 + tid) * 8 + e];
    __syncthreads();
    for (int hc = 0; hc < 4096; hc += 64) {
      float a0 = 0.f, a1 = 0.f;
      const float* w1p = w1 + (size_t)e * DH + hc + hl;
      for (int d = 0; d < 1024; ++d) {
        float wvv = w1p[(size_t)d * 4096];
        a0 += xs[wv * 2 + 0][d] * wvv;
        a1 += xs[wv * 2 + 1][d] * wvv;
      }
      __syncthreads();
      gs[wv * 2 + 0][hl] =
          ps[wv * 2 + 0] * gelu_f(a0 + b1[(size_t)e * 4096 + hc + hl]);
      gs[wv * 2 + 1][hl] =
          ps[wv * 2 + 1] * gelu_f(a1 + b1[(size_t)e * 4096 + hc + hl]);
      __syncthreads();
      const float* w2p = w2 + (size_t)e * DH + (size_t)hc * 1024 + d0;
      for (int hh = 0; hh < 64; ++hh) {
        float g = gs[tt][hh];
#pragma unroll
        for (int jb = 0; jb < 8; ++jb) {
          f32x4 w4 = *(const f32x4*)(w2p + (size_t)hh * 1024 + jb * 4);
#pragma unroll
          for (int j2 = 0; j2 < 4; ++j2) acc[jb * 4 + j2] += g * w4[j2];
        }
      }
    }
#pragma unroll
    for (int j = 0; j < 32; ++j)
      acc[j] += ps[tt] * b2[(size_t)e * 1024 + d0 + j];
    __syncthreads();
  }
  float* yp = y + (size_t)(t0 + tt) * 1024 + d0;
#pragma unroll
  for (int jb = 0; jb < 8; ++jb) {
    f32x4 o = {acc[jb * 4], acc[jb * 4 + 1], acc[jb * 4 + 2], acc[jb * 4 + 3]};
    *(f32x4*)(yp + jb * 4) = o;
  }
}

// ---------------------------------------------------------------------------
extern "C" void kernel_launch(void* const* d_in, const int* in_sizes, int n_in,
                              void* d_out, int out_size, void* d_ws,
                              size_t ws_size, hipStream_t stream)
{
  const float* x  = (const float*)d_in[0];  // [2048,1024]
  const float* rw = (const float*)d_in[1];  // [1024,8]
  const float* rb = (const float*)d_in[2];  // [8]
  const float* w1 = (const float*)d_in[3];  // [8,1024,4096]
  const float* b1 = (const float*)d_in[4];  // [8,4096]
  const float* w2 = (const float*)d_in[5];  // [8,4096,1024]
  const float* b2 = (const float*)d_in[6];  // [8,1024]
  float* y = (float*)d_out;                   // [2048,1024]
  float* probs_out = y + (size_t)2048 * 1024; // [2048,8]

  const size_t DH = (size_t)1024 * 4096;
  const size_t BASE = (64 << 10) + (size_t)2048 * 1024 * 4 +
                      (size_t)2048 * 1024 * 2;                     // P|accb|xb
  const size_t TA = BASE + 8 * DH * 2 + (size_t)2048 * 32768 * 2;  // ~214 MB
  const size_t TB = BASE + DH * 2 + (size_t)2048 * 4096 * 2;       // ~37.9 MB

  char* ws = (char*)d_ws;
  float* P = (float*)ws;
  float* accb = (float*)(ws + (64 << 10));
  __bf16* xb = (__bf16*)(ws + (64 << 10) + (size_t)2048 * 1024 * 4);
  char* ws2 = ws + BASE;

  if (ws_size >= TA) {
    router_kernel<<<512, 256, 0, stream>>>(x, rw, rb, P, probs_out);
    hipMemsetAsync(accb, 0, (size_t)2048 * 1024 * 4, stream);
    cvt_kernel<<<1024, 256, 0, stream>>>(x, xb);
    __bf16* WT = (__bf16*)ws2;      // 64 MB: W1T, then reused as W2T
    __bf16* Hs = WT + 8 * DH;       // [2048][32768] bf16
    transconv_kernel<<<dim3(1, 64, 8), 256, 0, stream>>>(
        w1, WT, 1024, 4096, 64, 1024, DH);
    gemm1_kernel<<<dim3(8, 16, 8), 512, 0, stream>>>(xb, WT, b1, P, Hs,
                                                     32768, 0, DH);
    transconv_kernel<<<dim3(4, 16, 8), 256, 0, stream>>>(
        w2, WT, 4096, 1024, 64, 32768, 4096);
    gemm2_kernel<<<dim3(8, 4, 8), 512, 0, stream>>>(Hs, WT, accb, 32768,
                                                    32768, 4096, 4096);
    finalize_kernel<<<2048, 256, 0, stream>>>(accb, P, b2, y);
  } else if (ws_size >= TB) {
    router_kernel<<<512, 256, 0, stream>>>(x, rw, rb, P, probs_out);
    hipMemsetAsync(accb, 0, (size_t)2048 * 1024 * 4, stream);
    cvt_kernel<<<1024, 256, 0, stream>>>(x, xb);
    __bf16* WT = (__bf16*)ws2;      // 8 MB
    __bf16* HsE = WT + DH;          // 16 MB
    for (int e = 0; e < 8; ++e) {
      transconv_kernel<<<dim3(1, 64, 1), 256, 0, stream>>>(
          w1 + e * DH, WT, 1024, 4096, 64, 1024, 0);
      gemm1_kernel<<<dim3(8, 16, 1), 512, 0, stream>>>(xb, WT, b1, P, HsE,
                                                       4096, e, 0);
      transconv_kernel<<<dim3(4, 16, 1), 256, 0, stream>>>(
          w2 + e * DH, WT, 4096, 1024, 64, 4096, 0);
      gemm2_kernel<<<dim3(8, 4, 4), 512, 0, stream>>>(HsE, WT, accb, 4096,
                                                      4096, 1024, 1024);
    }
    finalize_kernel<<<2048, 256, 0, stream>>>(accb, P, b2, y);
  } else {
    router_kernel<<<512, 256, 0, stream>>>(x, rw, rb, (float*)nullptr,
                                           probs_out);
    fused_naive_kernel<<<256, 256, 0, stream>>>(x, w1, b1, w2, b2, probs_out,
                                                y);
  }
}

// Round 3
// 620.037 us; speedup vs baseline: 1.1755x; 1.1755x over previous
//
#include <hip/hip_runtime.h>
#include <math.h>

// ============================================================================
// MoE FFN (dense, E=8): y = sum_e softmax(x@Wr)[:,e] * (gelu(x@W1_e+b1_e)@W2_e+b2_e)
// T=2048, D=1024, H=4096, E=8. FP32 in/out; bf16 MFMA compute.
// R6 -> R7: (1) faithful m201 8-phase mainloop: BK=64, dbuf x (A 2half + B
// 2half) = 128 KiB, per K-tile 4 phases {ds-reads quadrant | stage 1 half |
// barrier | 16 MFMA | barrier}, vmcnt(4) once per tile (never 0 in steady
// state), setprio(1) around MFMA, sched_barrier(0) fencing every s_barrier.
// Stage ledger: ph0:A0(t+1) ph1:A1(t+1) ph2:B0(t+2) ph3:B1(t+2)+vmcnt(4).
// XOR swizzle chunk^=(row&7) on GLL source / ds_read (T2 both-sides).
// (2) LDS-tiled 64x64 transconv (coalesced both sides; old one had lanes
// 64KB apart on reads).
// ws tiers: A >=214MB (batched), B >=37.9MB (per-expert), D zero-ws fallback.
// ============================================================================

typedef float f32x4 __attribute__((ext_vector_type(4)));
typedef __bf16 bf16x8 __attribute__((ext_vector_type(8)));

#define GLL16(gp, lp)                                                          \
  __builtin_amdgcn_global_load_lds(                                            \
      (const __attribute__((address_space(1))) void*)(gp),                     \
      (__attribute__((address_space(3))) void*)(lp), 16, 0, 0)

// Branch-free GELU: erf via Abramowitz-Stegun 7.1.26 (|err| <= 1.5e-7).
__device__ __forceinline__ float gelu_f(float h) {
  float x = h * 0.70710678118654752f;
  float ax = fabsf(x);
  float t = __builtin_amdgcn_rcpf(fmaf(0.3275911f, ax, 1.0f));
  float p = fmaf(1.061405429f, t, -1.453152027f);
  p = fmaf(p, t, 1.421413741f);
  p = fmaf(p, t, -0.284496736f);
  p = fmaf(p, t, 0.254829592f);
  float e = __expf(-x * x);
  float erfv = fmaf(-p * t, e, 1.0f);
  erfv = copysignf(erfv, x);
  return 0.5f * h * (1.0f + erfv);
}

// ---------------------------------------------------------------------------
// Router: logits = x @ rw + rb (fp32), softmax -> P (ws) + probs_out (d_out)
// ---------------------------------------------------------------------------
__global__ void router_kernel(const float* __restrict__ x,
                              const float* __restrict__ rw,
                              const float* __restrict__ rb,
                              float* __restrict__ P,
                              float* __restrict__ probs_out)
{
  int gid = blockIdx.x * blockDim.x + threadIdx.x;
  int t = gid >> 6;
  int l = gid & 63;
  const float* xr = x + (size_t)t * 1024;
  float a[8];
#pragma unroll
  for (int e = 0; e < 8; ++e) a[e] = 0.f;
  for (int d = l; d < 1024; d += 64) {
    float xv = xr[d];
    f32x4 w0 = *(const f32x4*)(rw + d * 8);
    f32x4 w1 = *(const f32x4*)(rw + d * 8 + 4);
#pragma unroll
    for (int e = 0; e < 4; ++e) a[e] += xv * w0[e];
#pragma unroll
    for (int e = 0; e < 4; ++e) a[4 + e] += xv * w1[e];
  }
#pragma unroll
  for (int off = 32; off > 0; off >>= 1) {
#pragma unroll
    for (int e = 0; e < 8; ++e) a[e] += __shfl_down(a[e], off);
  }
  if (l == 0) {
#pragma unroll
    for (int e = 0; e < 8; ++e) a[e] += rb[e];
    float m = a[0];
#pragma unroll
    for (int e = 1; e < 8; ++e) m = fmaxf(m, a[e]);
    float s = 0.f;
#pragma unroll
    for (int e = 0; e < 8; ++e) { a[e] = __expf(a[e] - m); s += a[e]; }
    float inv = 1.f / s;
#pragma unroll
    for (int e = 0; e < 8; ++e) {
      float p = a[e] * inv;
      if (P) P[t * 8 + e] = p;
      probs_out[t * 8 + e] = p;
    }
  }
}

// ---------------------------------------------------------------------------
// Convert fp32 -> bf16 row-major (for x)
// ---------------------------------------------------------------------------
__global__ void cvt_kernel(const float* __restrict__ src,
                           __bf16* __restrict__ dst)
{
  size_t i = ((size_t)blockIdx.x * 256 + threadIdx.x) * 8;
  f32x4 v0 = *(const f32x4*)(src + i);
  f32x4 v1 = *(const f32x4*)(src + i + 4);
  bf16x8 o;
#pragma unroll
  for (int j = 0; j < 4; ++j) o[j] = (__bf16)v0[j];
#pragma unroll
  for (int j = 0; j < 4; ++j) o[4 + j] = (__bf16)v1[j];
  *(bf16x8*)(dst + i) = o;
}

// ---------------------------------------------------------------------------
// LDS-tiled transpose+convert: src fp32 [z][R][C] -> dst bf16 dst[c][dstLd]
// (+ z*zOff element offset within row) holding src[r][c] at [c][... + r].
// 64x64 tiles, 256 threads. Coalesced reads (256B/row-group) and coalesced
// bf16x8 stores (128B per 8 lanes). LDS [64][65] fp32: writes 2-way (free),
// reads 2-way (free).
// Grid: (R/64, C/64, Z).
// ---------------------------------------------------------------------------
__global__ void transconv_kernel(const float* __restrict__ src,
                                 __bf16* __restrict__ dst,
                                 int R, int C, size_t dstLd, size_t zOff)
{
  __shared__ float tile[64][65];
  size_t bs = (size_t)blockIdx.z * (size_t)R * (size_t)C;
  size_t dzo = (size_t)blockIdx.z * zOff;
  int r0 = blockIdx.x * 64, c0 = blockIdx.y * 64;
  int tr = threadIdx.x >> 4;         // 0..15
  int tc = (threadIdx.x & 15) * 4;   // 0,4,..,60
#pragma unroll
  for (int i = 0; i < 4; ++i) {
    f32x4 v = *(const f32x4*)(src + bs + (size_t)(r0 + tr + 16 * i) * C + c0 + tc);
#pragma unroll
    for (int j = 0; j < 4; ++j) tile[tr + 16 * i][tc + j] = v[j];
  }
  __syncthreads();
  int oc = threadIdx.x >> 3;         // 0..31
  int orr = (threadIdx.x & 7) * 8;   // 0,8,..,56
#pragma unroll
  for (int i = 0; i < 2; ++i) {
    int c = oc + 32 * i;
    bf16x8 o;
#pragma unroll
    for (int j = 0; j < 8; ++j) o[j] = (__bf16)tile[orr + j][c];
    *(bf16x8*)(dst + (size_t)(c0 + c) * dstLd + dzo + r0 + orr) = o;
  }
}

// ---------------------------------------------------------------------------
// 8-phase 256x256 MFMA mainloop, BK=64 (m201 template port).
// 8 waves (wm=w>>2, wn=w&3), per-wave out 128x64 = 8x4 frags of 16x16x32,
// 64 MFMA / K-tile / wave in 4 quadrant phases of 16.
// LDS: buf p (p=t&1) at p*65536: A-half h (128 rows x 128B) at h*16384,
// B-half h at 32768 + h*16384. Row r of a half: LDS[r][c] = global chunk
// c ^ (r&7) (16B chunks) -> conflict-free ds_read_b128 per 8-lane group.
// Stage: one half-tile per phase (2 GLL16/thread): ph0:A0(t+1) ph1:A1(t+1)
// ph2:B0(t+2) ph3:B1(t+2) then vmcnt(4) (leaves exactly B(t+2) in flight;
// proves A(t+1),B(t+1) landed). Overwrite safety: half X(t) is fully
// consumed (register-held, lgkm-waited before its MFMA) before the phase-end
// barrier that precedes X(t+k)'s stage issue.
// ---------------------------------------------------------------------------
__device__ __forceinline__ void mfma_loop256(
    const char* Ab, const char* Bb, size_t ldaB, size_t ldbB, int K,
    char* lds, f32x4 acc[8][4])
{
  const int tid = threadIdx.x;
  const int w = tid >> 6, l = tid & 63;
  const int wm = w >> 2, wn = w & 3;
  const int m16 = l & 15, q = l >> 4;
  const int swz = m16 & 7;
  const int aBase = wm * 16384 + m16 * 128;
  const int bBase = 32768 + (wn >> 1) * 16384 + ((wn & 1) * 64 + m16) * 128;
  // stage-side: lane l covers row (w*16 + g*8 + (l>>3)), LDS chunk (l&7),
  // sourcing global chunk (l&7)^((l>>3)&7).
  const int srcCh = ((l & 7) ^ ((l >> 3) & 7)) << 4;
  const size_t gA0 = (size_t)(w * 16 + (l >> 3)) * ldaB + srcCh;
  const size_t gB0 = (size_t)(w * 16 + (l >> 3)) * ldbB + srcCh;
  const int dstW = w * 2048;
  const int NT = K >> 6;

  bf16x8 af[4][2], bv[4][2];

#define STG_A(h, tau)                                                          \
  {                                                                            \
    char* d = lds + (((tau) & 1) * 65536) + (h) * 16384 + dstW;                \
    const char* g = Ab + gA0 + (size_t)((h) * 128) * ldaB + (size_t)(tau) * 128;\
    GLL16(g, d);                                                               \
    GLL16(g + 8 * ldaB, d + 1024);                                             \
  }
#define STG_B(h, tau)                                                          \
  {                                                                            \
    char* d = lds + (((tau) & 1) * 65536) + 32768 + (h) * 16384 + dstW;        \
    const char* g = Bb + gB0 + (size_t)((h) * 128) * ldbB + (size_t)(tau) * 128;\
    GLL16(g, d);                                                               \
    GLL16(g + 8 * ldbB, d + 1024);                                             \
  }
#define RD_A(lo, p)                                                            \
  _Pragma("unroll") for (int mi = 0; mi < 4; ++mi)                             \
  _Pragma("unroll") for (int ks = 0; ks < 2; ++ks)                             \
    af[mi][ks] = *(const bf16x8*)(lds + (p) * 65536 + aBase +                  \
        ((lo) * 4 + mi) * 2048 + (((ks * 4 + q) ^ swz) << 4));
#define RD_B(no, p)                                                            \
  _Pragma("unroll") for (int nj = 0; nj < 2; ++nj)                             \
  _Pragma("unroll") for (int ks = 0; ks < 2; ++ks)                             \
    bv[(no) * 2 + nj][ks] = *(const bf16x8*)(lds + (p) * 65536 + bBase +       \
        ((no) * 2 + nj) * 2048 + (((ks * 4 + q) ^ swz) << 4));
#define MM(lo, no)                                                             \
  __builtin_amdgcn_s_setprio(1);                                               \
  _Pragma("unroll") for (int mi = 0; mi < 4; ++mi)                             \
  _Pragma("unroll") for (int nj = 0; nj < 2; ++nj)                             \
  _Pragma("unroll") for (int ks = 0; ks < 2; ++ks)                             \
    acc[(lo) * 4 + mi][(no) * 2 + nj] =                                        \
        __builtin_amdgcn_mfma_f32_16x16x32_bf16(                               \
            af[mi][ks], bv[(no) * 2 + nj][ks],                                 \
            acc[(lo) * 4 + mi][(no) * 2 + nj], 0, 0, 0);                       \
  __builtin_amdgcn_s_setprio(0);
#define SB __builtin_amdgcn_sched_barrier(0)
#define BAR { SB; __builtin_amdgcn_s_barrier(); SB; }
#define VMW(n) asm volatile("s_waitcnt vmcnt(" #n ")" ::: "memory")

  // Prologue: tile 0 (all 4 halves) + B halves of tile 1 (staged nowhere in
  // the loop for t=0). vmcnt(4) leaves B(1) outstanding, tile 0 landed.
  STG_A(0, 0); STG_A(1, 0); STG_B(0, 0); STG_B(1, 0);
  STG_B(0, 1); STG_B(1, 1);
  VMW(4);
  BAR;

  int t = 0;
  for (; t < NT - 2; ++t) {
    const int p = t & 1;
    // ph0: quadrant (mi0-3 x nj0-1)
    RD_A(0, p); RD_B(0, p);
    STG_A(0, t + 1);
    BAR; MM(0, 0); BAR;
    // ph1: (mi0-3 x nj2-3)
    RD_B(1, p);
    STG_A(1, t + 1);
    BAR; MM(0, 1); BAR;
    // ph2: (mi4-7 x nj0-1)
    RD_A(1, p);
    STG_B(0, t + 2);
    BAR; MM(1, 0); BAR;
    // ph3: (mi4-7 x nj2-3), no reads; vmcnt once per K-tile
    STG_B(1, t + 2);
    BAR; MM(1, 1); SB; VMW(4); BAR;
  }
  {  // t = NT-2: stage only A(NT-1); drain fully at ph3
    const int p = t & 1;
    RD_A(0, p); RD_B(0, p);
    STG_A(0, t + 1);
    BAR; MM(0, 0); BAR;
    RD_B(1, p);
    STG_A(1, t + 1);
    BAR; MM(0, 1); BAR;
    RD_A(1, p);
    BAR; MM(1, 0); BAR;
    BAR; MM(1, 1); SB; VMW(0); BAR;
    ++t;
  }
  {  // t = NT-1: all resident, no stages -> no barriers needed
    const int p = t & 1;
    RD_A(0, p); RD_B(0, p);
    MM(0, 0);
    RD_B(1, p);
    MM(0, 1);
    RD_A(1, p);
    MM(1, 0);
    MM(1, 1);
  }
#undef STG_A
#undef STG_B
#undef RD_A
#undef RD_B
#undef MM
#undef SB
#undef BAR
#undef VMW
}

// bijective XCD-chunked block swizzle (nwg % 8 == 0 for all our grids)
__device__ __forceinline__ int xcd_swz(int id, int nwg) {
  return ((nwg & 7) == 0) ? ((id & 7) * (nwg >> 3) + (id >> 3)) : id;
}

// ---------------------------------------------------------------------------
// GEMM1: Hs[t, zcol+h] = P[t,e] * gelu(Xb @ W1T_e^T + b1_e)   (bf16 store)
// grid (8, N/256, Z), 512 threads
// ---------------------------------------------------------------------------
__global__ __launch_bounds__(512, 2) void gemm1_kernel(
    const __bf16* __restrict__ X, const __bf16* __restrict__ W1T,
    const float* __restrict__ b1, const float* __restrict__ P,
    __bf16* __restrict__ Hs, int hs_ld, int e_off, size_t b_zstride)
{
  __shared__ __align__(16) char lds[131072];
  const int nwg = gridDim.x * gridDim.y * gridDim.z;
  const int id = blockIdx.x + gridDim.x * (blockIdx.y + gridDim.y * blockIdx.z);
  const int wg = xcd_swz(id, nwg);
  const int bm = wg & 7;
  const int bn = (wg >> 3) % gridDim.y;
  const int z = wg / (gridDim.y << 3);
  const int e = z + e_off;

  f32x4 acc[8][4];
  const f32x4 z4 = {0.f, 0.f, 0.f, 0.f};
#pragma unroll
  for (int i = 0; i < 8; ++i)
#pragma unroll
    for (int j = 0; j < 4; ++j) acc[i][j] = z4;

  const char* A = (const char*)(X + (size_t)bm * 256 * 1024);
  const char* B = (const char*)(W1T + (size_t)z * b_zstride +
                                (size_t)bn * 256 * 1024);
  mfma_loop256(A, B, 2048, 2048, 1024, lds, acc);

  const int tid = threadIdx.x, w = tid >> 6, l = tid & 63;
  const int wm = w >> 2, wn = w & 3, q = l >> 4, m16 = l & 15;
  const int row0 = bm * 256 + wm * 128 + q * 4;
  const int colE = bn * 256 + wn * 64 + m16;
  const int zcol = (hs_ld == 4096) ? 0 : z * 4096;
  float b1v[4];
#pragma unroll
  for (int nj = 0; nj < 4; ++nj)
    b1v[nj] = b1[(size_t)e * 4096 + colE + nj * 16];
#pragma unroll
  for (int mi = 0; mi < 8; ++mi) {
    float pv[4];
#pragma unroll
    for (int r = 0; r < 4; ++r)
      pv[r] = P[(size_t)(row0 + mi * 16 + r) * 8 + e];
#pragma unroll
    for (int nj = 0; nj < 4; ++nj)
#pragma unroll
      for (int r = 0; r < 4; ++r) {
        float h = acc[mi][nj][r] + b1v[nj];
        float o = gelu_f(h) * pv[r];
        Hs[(size_t)(row0 + mi * 16 + r) * hs_ld + zcol + colE + nj * 16] =
            (__bf16)o;
      }
  }
}

// ---------------------------------------------------------------------------
// GEMM2: accb[t,d] += Hs_chunk @ W2T_chunk^T (split-K via z, fp32 atomics)
// grid (8, N/256, Z), 512 threads; per-block K = Kb at offset z*kz
// ---------------------------------------------------------------------------
__global__ __launch_bounds__(512, 2) void gemm2_kernel(
    const __bf16* __restrict__ Hs, const __bf16* __restrict__ W2T,
    float* __restrict__ accb, int lda, int ldb, int kz, int Kb)
{
  __shared__ __align__(16) char lds[131072];
  const int nwg = gridDim.x * gridDim.y * gridDim.z;
  const int id = blockIdx.x + gridDim.x * (blockIdx.y + gridDim.y * blockIdx.z);
  const int wg = xcd_swz(id, nwg);
  const int bm = wg & 7;
  const int bn = (wg >> 3) % gridDim.y;
  const int z = wg / (gridDim.y << 3);

  f32x4 acc[8][4];
  const f32x4 z4 = {0.f, 0.f, 0.f, 0.f};
#pragma unroll
  for (int i = 0; i < 8; ++i)
#pragma unroll
    for (int j = 0; j < 4; ++j) acc[i][j] = z4;

  const char* A = (const char*)(Hs + (size_t)bm * 256 * lda + (size_t)z * kz);
  const char* B = (const char*)(W2T + (size_t)bn * 256 * ldb + (size_t)z * kz);
  mfma_loop256(A, B, (size_t)lda * 2, (size_t)ldb * 2, Kb, lds, acc);

  const int tid = threadIdx.x, w = tid >> 6, l = tid & 63;
  const int wm = w >> 2, wn = w & 3, q = l >> 4, m16 = l & 15;
  const int row0 = bm * 256 + wm * 128 + q * 4;
  const int col0 = bn * 256 + wn * 64 + m16;
#pragma unroll
  for (int mi = 0; mi < 8; ++mi)
#pragma unroll
    for (int nj = 0; nj < 4; ++nj)
#pragma unroll
      for (int r = 0; r < 4; ++r)
        unsafeAtomicAdd(
            accb + (size_t)(row0 + mi * 16 + r) * 1024 + col0 + nj * 16,
            acc[mi][nj][r]);
}

// ---------------------------------------------------------------------------
// Finalize: y = accb + sum_e P*b2   (fp32)
// ---------------------------------------------------------------------------
__global__ void finalize_kernel(const float* __restrict__ accb,
                                const float* __restrict__ P,
                                const float* __restrict__ b2,
                                float* __restrict__ y)
{
  int idx = blockIdx.x * 256 + threadIdx.x;
  int t = idx >> 8;
  int d0 = (idx & 255) << 2;
  f32x4 a = *(const f32x4*)(accb + (size_t)t * 1024 + d0);
#pragma unroll
  for (int e = 0; e < 8; ++e) {
    float p = P[t * 8 + e];
    f32x4 b = *(const f32x4*)(b2 + (size_t)e * 1024 + d0);
#pragma unroll
    for (int c = 0; c < 4; ++c) a[c] += p * b[c];
  }
  *(f32x4*)(y + (size_t)t * 1024 + d0) = a;
}

// ---------------------------------------------------------------------------
// Tier D: zero-workspace fused VALU fallback (fp32)
// ---------------------------------------------------------------------------
__global__ __launch_bounds__(256) void fused_naive_kernel(
    const float* __restrict__ x, const float* __restrict__ w1,
    const float* __restrict__ b1, const float* __restrict__ w2,
    const float* __restrict__ b2, const float* __restrict__ probs,
    float* __restrict__ y)
{
  __shared__ float xs[8][1024];
  __shared__ float gs[8][64];
  __shared__ float ps[8];
  const int tid = threadIdx.x;
  const int t0 = blockIdx.x * 8;
  const size_t DH = (size_t)1024 * 4096;
  const int tt = tid >> 5;
  const int d0 = (tid & 31) * 32;
  float acc[32];
#pragma unroll
  for (int i = 0; i < 32; ++i) acc[i] = 0.f;
  {
    const f32x4* xsrc = (const f32x4*)(x + (size_t)t0 * 1024);
    f32x4* xdst = (f32x4*)&xs[0][0];
    for (int i = tid; i < 2048; i += 256) xdst[i] = xsrc[i];
  }
  const int wv = tid >> 6;
  const int hl = tid & 63;
  for (int e = 0; e < 8; ++e) {
    if (tid < 8) ps[tid] = probs[(size_t)(t0 + tid) * 8 + e];
    __syncthreads();
    for (int hc = 0; hc < 4096; hc += 64) {
      float a0 = 0.f, a1 = 0.f;
      const float* w1p = w1 + (size_t)e * DH + hc + hl;
      for (int d = 0; d < 1024; ++d) {
        float wvv = w1p[(size_t)d * 4096];
        a0 += xs[wv * 2 + 0][d] * wvv;
        a1 += xs[wv * 2 + 1][d] * wvv;
      }
      __syncthreads();
      gs[wv * 2 + 0][hl] =
          ps[wv * 2 + 0] * gelu_f(a0 + b1[(size_t)e * 4096 + hc + hl]);
      gs[wv * 2 + 1][hl] =
          ps[wv * 2 + 1] * gelu_f(a1 + b1[(size_t)e * 4096 + hc + hl]);
      __syncthreads();
      const float* w2p = w2 + (size_t)e * DH + (size_t)hc * 1024 + d0;
      for (int hh = 0; hh < 64; ++hh) {
        float g = gs[tt][hh];
#pragma unroll
        for (int jb = 0; jb < 8; ++jb) {
          f32x4 w4 = *(const f32x4*)(w2p + (size_t)hh * 1024 + jb * 4);
#pragma unroll
          for (int j2 = 0; j2 < 4; ++j2) acc[jb * 4 + j2] += g * w4[j2];
        }
      }
    }
#pragma unroll
    for (int j = 0; j < 32; ++j)
      acc[j] += ps[tt] * b2[(size_t)e * 1024 + d0 + j];
    __syncthreads();
  }
  float* yp = y + (size_t)(t0 + tt) * 1024 + d0;
#pragma unroll
  for (int jb = 0; jb < 8; ++jb) {
    f32x4 o = {acc[jb * 4], acc[jb * 4 + 1], acc[jb * 4 + 2], acc[jb * 4 + 3]};
    *(f32x4*)(yp + jb * 4) = o;
  }
}

// ---------------------------------------------------------------------------
extern "C" void kernel_launch(void* const* d_in, const int* in_sizes, int n_in,
                              void* d_out, int out_size, void* d_ws,
                              size_t ws_size, hipStream_t stream)
{
  const float* x  = (const float*)d_in[0];  // [2048,1024]
  const float* rw = (const float*)d_in[1];  // [1024,8]
  const float* rb = (const float*)d_in[2];  // [8]
  const float* w1 = (const float*)d_in[3];  // [8,1024,4096]
  const float* b1 = (const float*)d_in[4];  // [8,4096]
  const float* w2 = (const float*)d_in[5];  // [8,4096,1024]
  const float* b2 = (const float*)d_in[6];  // [8,1024]
  float* y = (float*)d_out;                   // [2048,1024]
  float* probs_out = y + (size_t)2048 * 1024; // [2048,8]

  const size_t DH = (size_t)1024 * 4096;
  const size_t BASE = (64 << 10) + (size_t)2048 * 1024 * 4 +
                      (size_t)2048 * 1024 * 2;                     // P|accb|xb
  const size_t TA = BASE + 8 * DH * 2 + (size_t)2048 * 32768 * 2;  // ~214 MB
  const size_t TB = BASE + DH * 2 + (size_t)2048 * 4096 * 2;       // ~37.9 MB

  char* ws = (char*)d_ws;
  float* P = (float*)ws;
  float* accb = (float*)(ws + (64 << 10));
  __bf16* xb = (__bf16*)(ws + (64 << 10) + (size_t)2048 * 1024 * 4);
  char* ws2 = ws + BASE;

  if (ws_size >= TA) {
    router_kernel<<<512, 256, 0, stream>>>(x, rw, rb, P, probs_out);
    hipMemsetAsync(accb, 0, (size_t)2048 * 1024 * 4, stream);
    cvt_kernel<<<1024, 256, 0, stream>>>(x, xb);
    __bf16* WT = (__bf16*)ws2;      // 64 MB: W1T, then reused as W2T
    __bf16* Hs = WT + 8 * DH;       // [2048][32768] bf16
    transconv_kernel<<<dim3(16, 64, 8), 256, 0, stream>>>(
        w1, WT, 1024, 4096, 1024, DH);
    gemm1_kernel<<<dim3(8, 16, 8), 512, 0, stream>>>(xb, WT, b1, P, Hs,
                                                     32768, 0, DH);
    transconv_kernel<<<dim3(64, 16, 8), 256, 0, stream>>>(
        w2, WT, 4096, 1024, 32768, 4096);
    gemm2_kernel<<<dim3(8, 4, 8), 512, 0, stream>>>(Hs, WT, accb, 32768,
                                                    32768, 4096, 4096);
    finalize_kernel<<<2048, 256, 0, stream>>>(accb, P, b2, y);
  } else if (ws_size >= TB) {
    router_kernel<<<512, 256, 0, stream>>>(x, rw, rb, P, probs_out);
    hipMemsetAsync(accb, 0, (size_t)2048 * 1024 * 4, stream);
    cvt_kernel<<<1024, 256, 0, stream>>>(x, xb);
    __bf16* WT = (__bf16*)ws2;      // 8 MB
    __bf16* HsE = WT + DH;          // 16 MB
    for (int e = 0; e < 8; ++e) {
      transconv_kernel<<<dim3(16, 64, 1), 256, 0, stream>>>(
          w1 + e * DH, WT, 1024, 4096, 1024, 0);
      gemm1_kernel<<<dim3(8, 16, 1), 512, 0, stream>>>(xb, WT, b1, P, HsE,
                                                       4096, e, 0);
      transconv_kernel<<<dim3(64, 16, 1), 256, 0, stream>>>(
          w2 + e * DH, WT, 4096, 1024, 4096, 0);
      gemm2_kernel<<<dim3(8, 4, 4), 512, 0, stream>>>(HsE, WT, accb, 4096,
                                                      4096, 1024, 1024);
    }
    finalize_kernel<<<2048, 256, 0, stream>>>(accb, P, b2, y);
  } else {
    router_kernel<<<512, 256, 0, stream>>>(x, rw, rb, (float*)nullptr,
                                           probs_out);
    fused_naive_kernel<<<256, 256, 0, stream>>>(x, w1, b1, w2, b2, probs_out,
                                                y);
  }
}